// Round 5
// baseline (425.882 us; speedup 1.0000x reference)
//
#include <hip/hip_runtime.h>
#include <math.h>

#define B_ 256
#define S_ 200
#define D_ 256
#define H_ 8
#define DH_ 32
#define BS_ (B_*S_)            // 51200 rows
#define NEL ((size_t)BS_*D_)   // 13107200

typedef __attribute__((ext_vector_type(8))) short bhalf8;  // 8 bf16 in 4 VGPRs
typedef __attribute__((ext_vector_type(4))) float fx4;

__device__ __forceinline__ unsigned short f2bf(float f) {
  union { float f; unsigned u; } x; x.f = f;
  unsigned r = x.u + 0x7FFFu + ((x.u >> 16) & 1u);   // RNE
  return (unsigned short)(r >> 16);
}
__device__ __forceinline__ float bf2f(unsigned short h) {
  union { unsigned u; float f; } x; x.u = ((unsigned)h) << 16; return x.f;
}
__device__ __forceinline__ bhalf8 pack8(float4 a, float4 b) {
  bhalf8 p;
  p[0] = (short)f2bf(a.x); p[1] = (short)f2bf(a.y);
  p[2] = (short)f2bf(a.z); p[3] = (short)f2bf(a.w);
  p[4] = (short)f2bf(b.x); p[5] = (short)f2bf(b.y);
  p[6] = (short)f2bf(b.z); p[7] = (short)f2bf(b.w);
  return p;
}
__device__ __forceinline__ float wave_reduce_sum(float v) {
#pragma unroll
  for (int o = 32; o >= 1; o >>= 1) v += __shfl_xor(v, o, 64);
  return v;
}

// ---------------- weight f32 -> bf16 convert (Wb|Wo|W1 concatenated) ----------------
__global__ __launch_bounds__(256) void conv_w_kernel(
    const float* __restrict__ Wb, const float* __restrict__ Wo,
    const float* __restrict__ W1, short* __restrict__ dst) {
  const int t = blockIdx.x * 256 + threadIdx.x;      // 24576 threads, 8 elems each
  const int w = t >> 13, r = (t & 8191) * 8;
  const float* src = (w == 0) ? Wb : ((w == 1) ? Wo : W1);
  float4 f0 = *(const float4*)(src + r), f1 = *(const float4*)(src + r + 4);
  *(bhalf8*)(dst + (w << 16) + r) = pack8(f0, f1);
}

// ---------------- LayerNorm (both tensors), bf16 out: one wave per row ----------------
__global__ __launch_bounds__(256) void ln2_kernel(
    const float* __restrict__ ximg, const float* __restrict__ xtit,
    const float* __restrict__ a_img, const float* __restrict__ b_img,
    const float* __restrict__ a_tit, const float* __restrict__ b_tit,
    short* __restrict__ yimg, short* __restrict__ ytit) {
  const int wave = threadIdx.x >> 6, lane = threadIdx.x & 63;
  const int second = (blockIdx.x >= BS_ / 4) ? 1 : 0;
  const int row = (blockIdx.x - second * (BS_ / 4)) * 4 + wave;
  const float* x = second ? xtit : ximg;
  const float* a = second ? a_tit : a_img;
  const float* b = second ? b_tit : b_img;
  short* y = second ? ytit : yimg;
  float4 v = ((const float4*)(x + (size_t)row * D_))[lane];
  float s  = v.x + v.y + v.z + v.w;
  float ss = v.x*v.x + v.y*v.y + v.z*v.z + v.w*v.w;
  s = wave_reduce_sum(s); ss = wave_reduce_sum(ss);
  float mean = s * (1.0f / D_);
  float var  = fmaxf((ss - (float)D_ * mean * mean) * (1.0f / (D_ - 1)), 0.0f);
  float inv  = 1.0f / (sqrtf(var) + 1e-6f);
  float4 av = ((const float4*)a)[lane];
  float4 bv = ((const float4*)b)[lane];
  ushort4 o;
  o.x = f2bf(av.x * (v.x - mean) * inv + bv.x);
  o.y = f2bf(av.y * (v.y - mean) * inv + bv.y);
  o.z = f2bf(av.z * (v.z - mean) * inv + bv.z);
  o.w = f2bf(av.w * (v.w - mean) * inv + bv.w);
  *(ushort4*)(y + (size_t)row * D_ + lane * 4) = o;
}

// ---------------- LDS-free bf16 MFMA GEMM: C = A @ W^T ----------------
// Block = 256 thr (4 waves); wave owns 32 m-rows x all 256 n-cols (acc[2][16] AGPR).
// All 16 A-fragments (K=256) issued upfront -> deep MLP on the HBM stream.
// W fragments read per-use from global (128 KB, L2-resident, shared by all blocks).
// EPI 0: outb = C + bias[n] + bf(addb)        (kk, bf16)
// EPI 1: h1 = C + bias[n] + addf (f32 regs); outb2 = bf(h1); outb = bf(LN(h1))
// EPI 2: z = (C + bias[n]) * sf[m%S]; outf = bf(addb) + gelu(z)   (f32)
template <int EPI>
__global__ __launch_bounds__(256, 2) void gemm_k(
    const short* __restrict__ A, const short* __restrict__ W,
    const float* __restrict__ bias,
    const short* __restrict__ addb,
    const float* __restrict__ addf,
    const float* __restrict__ ga, const float* __restrict__ gb,
    const float* __restrict__ sf,
    short* __restrict__ outb, short* __restrict__ outb2,
    float* __restrict__ outf) {
  const int tid = threadIdx.x;
  const int wv = tid >> 6, lane = tid & 63, g = lane >> 4, cc = lane & 15;
  const int mrow0 = blockIdx.x * 128 + wv * 32;

  // whole-K A fragments: rows mrow0+cc, mrow0+16+cc; 16 x 16B loads in flight
  bhalf8 a[2][8];
#pragma unroll
  for (int kc = 0; kc < 8; kc++) {
    a[0][kc] = *(const bhalf8*)(A + (size_t)(mrow0 + cc) * D_ + kc * 32 + g * 8);
    a[1][kc] = *(const bhalf8*)(A + (size_t)(mrow0 + 16 + cc) * D_ + kc * 32 + g * 8);
  }
  fx4 acc[2][16];
#pragma unroll
  for (int i = 0; i < 2; i++)
#pragma unroll
    for (int j = 0; j < 16; j++) acc[i][j] = (fx4){0.f, 0.f, 0.f, 0.f};

#pragma unroll
  for (int j = 0; j < 16; j++) {
#pragma unroll
    for (int kc = 0; kc < 8; kc++) {
      bhalf8 fb = *(const bhalf8*)(W + (size_t)(j * 16 + cc) * D_ + kc * 32 + g * 8);
      acc[0][j] = __builtin_amdgcn_mfma_f32_16x16x32_bf16(a[0][kc], fb, acc[0][j], 0, 0, 0);
      acc[1][j] = __builtin_amdgcn_mfma_f32_16x16x32_bf16(a[1][kc], fb, acc[1][j], 0, 0, 0);
    }
  }

  float bias_r[16];
#pragma unroll
  for (int j = 0; j < 16; j++) bias_r[j] = bias[j * 16 + cc];

  if (EPI == 0) {
#pragma unroll
    for (int i = 0; i < 2; i++)
#pragma unroll
      for (int r = 0; r < 4; r++) {
        const size_t m = mrow0 + i * 16 + 4 * g + r;
#pragma unroll
        for (int j = 0; j < 16; j++) {
          const int n = j * 16 + cc;
          float v = acc[i][j][r] + bias_r[j] + bf2f((unsigned short)addb[m * D_ + n]);
          outb[m * D_ + n] = (short)f2bf(v);
        }
      }
  } else if (EPI == 1) {
    float ga_r[16], gb_r[16];
#pragma unroll
    for (int j = 0; j < 16; j++) { ga_r[j] = ga[j * 16 + cc]; gb_r[j] = gb[j * 16 + cc]; }
#pragma unroll
    for (int i = 0; i < 2; i++)
#pragma unroll
      for (int r = 0; r < 4; r++) {
        const size_t m = mrow0 + i * 16 + 4 * g + r;
        float s = 0.f, ss = 0.f;
#pragma unroll
        for (int j = 0; j < 16; j++) {
          float v = acc[i][j][r] + bias_r[j] + addf[m * D_ + j * 16 + cc];
          outb2[m * D_ + j * 16 + cc] = (short)f2bf(v);
          acc[i][j][r] = v;
          s += v; ss += v * v;
        }
        s  += __shfl_xor(s, 1);  s += __shfl_xor(s, 2);  s += __shfl_xor(s, 4);  s += __shfl_xor(s, 8);
        ss += __shfl_xor(ss, 1); ss += __shfl_xor(ss, 2); ss += __shfl_xor(ss, 4); ss += __shfl_xor(ss, 8);
        const float mean = s * (1.0f / D_);
        const float var  = fmaxf((ss * (1.0f / D_) - mean * mean) * ((float)D_ / (D_ - 1)), 0.0f);
        const float inv  = 1.0f / (sqrtf(var) + 1e-6f);
#pragma unroll
        for (int j = 0; j < 16; j++) {
          float h = (acc[i][j][r] - mean) * inv * ga_r[j] + gb_r[j];
          outb[m * D_ + j * 16 + cc] = (short)f2bf(h);
        }
      }
  } else {
#pragma unroll
    for (int i = 0; i < 2; i++)
#pragma unroll
      for (int r = 0; r < 4; r++) {
        const size_t m = mrow0 + i * 16 + 4 * g + r;
        const float sfr = sf[(int)(m % S_)];
#pragma unroll
        for (int j = 0; j < 16; j++) {
          const int n = j * 16 + cc;
          float z = (acc[i][j][r] + bias_r[j]) * sfr;
          float gl = 0.5f * z * (1.0f + tanhf(0.79788456080286536f * (z + 0.044715f * z * z * z)));
          outf[m * D_ + n] = bf2f((unsigned short)addb[m * D_ + n]) + gl;
        }
      }
  }
}

// ---------------- MFMA attention: one block per (b,h), 4 independent waves ----------
__global__ __launch_bounds__(256) void attn_mfma_kernel(
    const short* __restrict__ imgb, const short* __restrict__ kkb,
    const int* __restrict__ mask, const float* __restrict__ scale_attn,
    short* __restrict__ ctxb) {
  __shared__ short K_s[208 * 40];      // [key][dh], pitch 40 (2-way banks)
  __shared__ short Vt_s[32 * 232];     // [dh][key], pitch 232
  __shared__ short P_s[4][16 * 232];   // per-wave P, pitch 232
  __shared__ int   m_s[224];
  const int tid = threadIdx.x;
  const int b = blockIdx.x >> 3, h = blockIdx.x & 7;
  const size_t base2 = (size_t)(b * S_) * D_ + h * DH_;   // in bf16 elems

  // stage K (bf16 copy): 200 rows x 4 chunks of 16B
  for (int i = tid; i < 800; i += 256) {
    const int row = i >> 2, ch = i & 3;
    *(bhalf8*)&K_s[row * 40 + ch * 8] = *(const bhalf8*)(kkb + base2 + (size_t)row * D_ + ch * 8);
  }
  // stage V^T: row-pairs packed as dwords
  for (int t = tid; t < 400; t += 256) {
    const int p = t >> 2, ch = t & 3;                      // rows 2p,2p+1; d-offset ch*8
    bhalf8 lo = *(const bhalf8*)(imgb + base2 + (size_t)(2 * p) * D_ + ch * 8);
    bhalf8 hi = *(const bhalf8*)(imgb + base2 + (size_t)(2 * p + 1) * D_ + ch * 8);
#pragma unroll
    for (int u = 0; u < 8; u++) {
      unsigned dw = (unsigned)(unsigned short)lo[u] | ((unsigned)(unsigned short)hi[u] << 16);
      *(unsigned*)&Vt_s[(ch * 8 + u) * 232 + 2 * p] = dw;
    }
  }
  // zero pads
  { const int row = 200 + (tid >> 5), col = tid & 31; K_s[row * 40 + col] = 0; }          // K rows 200..207
  { const int row = tid >> 3, k0 = 200 + (tid & 7) * 4;                                   // Vt k 200..231
    *(unsigned long long*)&Vt_s[row * 232 + k0] = 0ULL; }
  if (tid < 224) m_s[tid] = (tid < S_) ? mask[b * S_ + tid] : 0;

  const int wv = tid >> 6, lane = tid & 63;
  const int g = lane >> 4, c = lane & 15;
  short* Pw = &P_s[wv][0];
  { const int row = lane >> 2, colq = lane & 3;                                           // P cols 208..223
    *(unsigned long long*)&Pw[row * 232 + 208 + colq * 4] = 0ULL; }
  __syncthreads();

  const float rs32 = 0.17677669529663687f;  // 1/sqrt(32)
  const fx4 zero = {0.f, 0.f, 0.f, 0.f};
  for (int t = wv; t < 13; t += 4) {
    const int q0 = t * 16;
    int qr = q0 + c; if (qr > S_ - 1) qr = S_ - 1;
    bhalf8 af = *(const bhalf8*)(imgb + base2 + (size_t)qr * D_ + g * 8);

    fx4 st[13];
    __builtin_amdgcn_s_setprio(1);
#pragma unroll
    for (int t2 = 0; t2 < 13; t2++) {
      bhalf8 kf = *(const bhalf8*)&K_s[(t2 * 16 + c) * 40 + g * 8];
      st[t2] = __builtin_amdgcn_mfma_f32_16x16x32_bf16(af, kf, zero, 0, 0, 0);
    }
    __builtin_amdgcn_s_setprio(0);
    // scale + mask + row max (rows q0+4g+r; key = t2*16 + c)
    float sc[4], mx[4], l[4];
#pragma unroll
    for (int r = 0; r < 4; r++) {
      int q = q0 + 4 * g + r; if (q > S_ - 1) q = S_ - 1;
      sc[r] = scale_attn[h * S_ + q] * rs32;
      mx[r] = -1e30f; l[r] = 0.f;
    }
#pragma unroll
    for (int t2 = 0; t2 < 13; t2++) {
      const int msk = m_s[t2 * 16 + c];
#pragma unroll
      for (int r = 0; r < 4; r++) {
        float s = (msk != 0) ? st[t2][r] * sc[r] : -1e30f;
        st[t2][r] = s;
        mx[r] = fmaxf(mx[r], s);
      }
    }
#pragma unroll
    for (int r = 0; r < 4; r++) {
      mx[r] = fmaxf(mx[r], __shfl_xor(mx[r], 1));
      mx[r] = fmaxf(mx[r], __shfl_xor(mx[r], 2));
      mx[r] = fmaxf(mx[r], __shfl_xor(mx[r], 4));
      mx[r] = fmaxf(mx[r], __shfl_xor(mx[r], 8));
    }
#pragma unroll
    for (int t2 = 0; t2 < 13; t2++) {
#pragma unroll
      for (int r = 0; r < 4; r++) {
        float p = __expf(st[t2][r] - mx[r]);
        l[r] += p;
        Pw[(4 * g + r) * 232 + t2 * 16 + c] = (short)f2bf(p);
      }
    }
#pragma unroll
    for (int r = 0; r < 4; r++) {
      l[r] += __shfl_xor(l[r], 1);
      l[r] += __shfl_xor(l[r], 2);
      l[r] += __shfl_xor(l[r], 4);
      l[r] += __shfl_xor(l[r], 8);
    }
    // PV over 7 k-chunks of 32
    fx4 o0 = zero, o1 = zero;
    __builtin_amdgcn_s_setprio(1);
#pragma unroll
    for (int ch = 0; ch < 7; ch++) {
      bhalf8 pf = *(const bhalf8*)&Pw[c * 232 + ch * 32 + g * 8];
      bhalf8 v0 = *(const bhalf8*)&Vt_s[c * 232 + ch * 32 + g * 8];
      bhalf8 v1 = *(const bhalf8*)&Vt_s[(16 + c) * 232 + ch * 32 + g * 8];
      o0 = __builtin_amdgcn_mfma_f32_16x16x32_bf16(pf, v0, o0, 0, 0, 0);
      o1 = __builtin_amdgcn_mfma_f32_16x16x32_bf16(pf, v1, o1, 0, 0, 0);
    }
    __builtin_amdgcn_s_setprio(0);
#pragma unroll
    for (int r = 0; r < 4; r++) {
      const int q = q0 + 4 * g + r;
      if (q < S_) {
        const float inv = 1.0f / l[r];
        ctxb[base2 + (size_t)q * D_ + c]      = (short)f2bf(o0[r] * inv);
        ctxb[base2 + (size_t)q * D_ + 16 + c] = (short)f2bf(o1[r] * inv);
      }
    }
  }
}

extern "C" void kernel_launch(void* const* d_in, const int* in_sizes, int n_in,
                              void* d_out, int out_size, void* d_ws, size_t ws_size,
                              hipStream_t stream) {
  const float* hidden_img   = (const float*)d_in[0];
  const float* hidden_title = (const float*)d_in[1];
  const int*   mask         = (const int*)d_in[2];
  const float* a_img   = (const float*)d_in[3];
  const float* b_img   = (const float*)d_in[4];
  const float* a_title = (const float*)d_in[5];
  const float* b_title = (const float*)d_in[6];
  const float* Wb = (const float*)d_in[7];
  const float* bb = (const float*)d_in[8];
  const float* Wo = (const float*)d_in[9];
  const float* bo = (const float*)d_in[10];
  const float* scale_attn = (const float*)d_in[11];
  const float* a_out = (const float*)d_in[12];
  const float* b_out = (const float*)d_in[13];
  const float* W1 = (const float*)d_in[14];
  const float* b1 = (const float*)d_in[15];
  const float* scale_ffn = (const float*)d_in[16];
  float* out = (float*)d_out;

  char* wsb = (char*)d_ws;
  short* img_nb = (short*)(wsb);                   // LN(img) bf16 (Q,V)
  short* kkb    = (short*)(wsb + 26214400);        // kk bf16 (attn K)
  short* ctxb   = (short*)(wsb + 52428800);        // title_n bf16, then ctx bf16
  short* h1b    = (short*)(wsb + 78643200);        // h1 bf16
  short* h1nb   = (short*)(wsb + 104857600);       // LN(h1) bf16
  short* w16    = (short*)(wsb + 131072000);       // Wb|Wo|W1 bf16

  conv_w_kernel<<<dim3(96), 256, 0, stream>>>(Wb, Wo, W1, w16);
  ln2_kernel<<<dim3(2 * BS_ / 4), 256, 0, stream>>>(hidden_img, hidden_title,
      a_img, b_img, a_title, b_title, img_nb, ctxb);
  // kk = title_n @ Wb^T + bb + img_n
  gemm_k<0><<<dim3(400), 256, 0, stream>>>(ctxb, w16, bb, img_nb,
      nullptr, nullptr, nullptr, nullptr, kkb, nullptr, nullptr);
  // ctx
  attn_mfma_kernel<<<dim3(B_ * H_), 256, 0, stream>>>(img_nb, kkb, mask, scale_attn, ctxb);
  // h1 = ctx @ Wo^T + bo + hidden_img ; h1b = bf16(h1), h1nb = LN(h1)
  gemm_k<1><<<dim3(400), 256, 0, stream>>>(ctxb, w16 + 65536, bo, nullptr,
      hidden_img, a_out, b_out, nullptr, h1nb, h1b, nullptr);
  // out = h1 + gelu(scale_ffn * (h1n @ W1^T + b1))
  gemm_k<2><<<dim3(400), 256, 0, stream>>>(h1nb, w16 + 131072, b1, h1b,
      nullptr, nullptr, nullptr, scale_ffn, nullptr, nullptr, out);
}